// Round 4
// baseline (998.929 us; speedup 1.0000x reference)
//
#include <hip/hip_runtime.h>
#include <hip/hip_bf16.h>

// Problem constants (from reference)
#define BATCH 8
#define NWIN  8      // vertical stripe windows per batch (RESO/WSP)
#define NH    8
#define HD    32
#define WIN   512    // HSP*WSP = 64*8 tokens per window
#define DIM   256
#define RESO  64
#define SEQL  4096

// Inputs float32, output float32 (reference dtypes). Internal staging bf16.

__device__ __forceinline__ unsigned short f2bf(float f) {
    union { float f; unsigned int i; } x; x.f = f;
    unsigned int r = x.i + 0x7fff + ((x.i >> 16) & 1);   // round-to-nearest-even
    return (unsigned short)(r >> 16);
}
// unpack a uint holding two bf16 (little-endian: low half = even element)
__device__ __forceinline__ void unp2(unsigned int u, float& lo, float& hi) {
    union { unsigned int i; float f; } a, b;
    a.i = u << 16; b.i = u & 0xffff0000u;
    lo = a.f; hi = b.f;
}

// ---------------------------------------------------------------------------
// Kernel 1: per-(window,head) flash attention + fused LePE epilogue.
// Grid: 512 blocks (64 windows x 8 heads), 256 threads; each thread owns query
// rows t=tid and t+256 (online softmax, fp32 accum). K,V for the (window,head)
// staged in LDS as bf16 (32KB+32KB; fp32->bf16 on stage). LePE depthwise 3x3
// reads the V LDS tile (window-local zero padding matches reference conv).
// Writes X[bw*512+t][head*32+d] bf16 into workspace.
// ---------------------------------------------------------------------------
__global__ __launch_bounds__(256)
void attn_lepe_kernel(const float* __restrict__ qkv,
                      const float* __restrict__ scale_p,
                      const float* __restrict__ conv_w,
                      const float* __restrict__ conv_b,
                      unsigned short* __restrict__ X)
{
    __shared__ alignas(16) unsigned short Klds[WIN * HD];
    __shared__ alignas(16) unsigned short Vlds[WIN * HD];
    __shared__ float cw[HD * 9];
    __shared__ float cb[HD];

    const int wh   = blockIdx.x;     // 0..511
    const int bw   = wh >> 3;        // global window 0..63
    const int head = wh & 7;
    const int b    = bw >> 3;        // batch
    const int wx   = bw & 7;         // stripe index (column block)
    const int tid  = threadIdx.x;

    const float scale = scale_p[0];
    const size_t plane = (size_t)BATCH * SEQL * DIM;
    const float* qg = qkv;
    const float* kg = qkv + plane;
    const float* vg = qkv + 2 * plane;

    // Stage K,V rows: token t=(h,wi) -> seq pos l = h*64 + wx*8 + wi
    for (int idx = tid; idx < WIN * 4; idx += 256) {
        const int t = idx >> 2, seg = idx & 3;       // seg = 8 channels
        const int h = t >> 3, wi = t & 7;
        const size_t goff = ((size_t)b * SEQL + (size_t)h * RESO + wx * 8 + wi) * DIM
                          + head * HD + seg * 8;
        const float4 k0 = *(const float4*)(kg + goff);
        const float4 k1 = *(const float4*)(kg + goff + 4);
        const float4 v0 = *(const float4*)(vg + goff);
        const float4 v1 = *(const float4*)(vg + goff + 4);
        ushort4 ka, kb, va, vb;
        ka.x = f2bf(k0.x); ka.y = f2bf(k0.y); ka.z = f2bf(k0.z); ka.w = f2bf(k0.w);
        kb.x = f2bf(k1.x); kb.y = f2bf(k1.y); kb.z = f2bf(k1.z); kb.w = f2bf(k1.w);
        va.x = f2bf(v0.x); va.y = f2bf(v0.y); va.z = f2bf(v0.z); va.w = f2bf(v0.w);
        vb.x = f2bf(v1.x); vb.y = f2bf(v1.y); vb.z = f2bf(v1.z); vb.w = f2bf(v1.w);
        *(ushort4*)&Klds[t * HD + seg * 8]     = ka;
        *(ushort4*)&Klds[t * HD + seg * 8 + 4] = kb;
        *(ushort4*)&Vlds[t * HD + seg * 8]     = va;
        *(ushort4*)&Vlds[t * HD + seg * 8 + 4] = vb;
    }
    for (int i = tid; i < HD * 9; i += 256)              // 288 entries > 256 threads
        cw[i] = conv_w[head * HD * 9 + i];               // [c][3][3] contiguous
    if (tid < HD) cb[tid] = conv_b[head * HD + tid];
    __syncthreads();

    const unsigned int* Kp = (const unsigned int*)Klds;
    const unsigned int* Vp = (const unsigned int*)Vlds;
    const bool mwin = (wx == 7);     // only the last stripe has a mask

    for (int rr = 0; rr < 2; ++rr) {
        const int t  = tid + rr * 256;
        const int h  = t >> 3, wi = t & 7;
        const size_t qoff = ((size_t)b * SEQL + (size_t)h * RESO + wx * 8 + wi) * DIM
                          + head * HD;

        // load q row (32 fp32), pre-scale
        float qr[HD];
        {
            const float4* qp = (const float4*)(qg + qoff);
            #pragma unroll
            for (int s4 = 0; s4 < 8; ++s4) {
                const float4 u = qp[s4];
                qr[s4 * 4 + 0] = u.x * scale;
                qr[s4 * 4 + 1] = u.y * scale;
                qr[s4 * 4 + 2] = u.z * scale;
                qr[s4 * 4 + 3] = u.w * scale;
            }
        }

        float m = -1e30f, lsum = 0.f;
        float o[HD];
        #pragma unroll
        for (int d = 0; d < HD; ++d) o[d] = 0.f;
        const bool qgrp = (wi < 4);

        for (int j = 0; j < WIN; ++j) {
            // s = q . k_j  (4 partial sums to break the dependency chain)
            float s0 = 0.f, s1 = 0.f, s2 = 0.f, s3 = 0.f;
            #pragma unroll
            for (int dd = 0; dd < 16; dd += 4) {
                float a0,a1,b0,b1,c0,c1,d0,d1;
                unp2(Kp[j * 16 + dd + 0], a0, a1);
                unp2(Kp[j * 16 + dd + 1], b0, b1);
                unp2(Kp[j * 16 + dd + 2], c0, c1);
                unp2(Kp[j * 16 + dd + 3], d0, d1);
                s0 += qr[2*dd + 0] * a0 + qr[2*dd + 1] * a1;
                s1 += qr[2*dd + 2] * b0 + qr[2*dd + 3] * b1;
                s2 += qr[2*dd + 4] * c0 + qr[2*dd + 5] * c1;
                s3 += qr[2*dd + 6] * d0 + qr[2*dd + 7] * d1;
            }
            float s = (s0 + s1) + (s2 + s3);
            if (mwin && (((j & 7) < 4) != qgrp)) s -= 100.f;  // shifted-window mask

            const float mn   = fmaxf(m, s);
            const float corr = __expf(m - mn);   // m=-1e30 first iter -> corr=0
            const float p    = __expf(s - mn);
            lsum = lsum * corr + p;
            #pragma unroll
            for (int dd = 0; dd < 16; ++dd) {
                float lo, hi; unp2(Vp[j * 16 + dd], lo, hi);
                o[2*dd]     = o[2*dd]     * corr + p * lo;
                o[2*dd + 1] = o[2*dd + 1] * corr + p * hi;
            }
            m = mn;
        }

        const float rl = 1.0f / lsum;
        #pragma unroll
        for (int d = 0; d < HD; ++d) o[d] = o[d] * rl + cb[d];

        // LePE: depthwise 3x3 over the window-local V image (zero pad at window edges)
        #pragma unroll
        for (int kh = -1; kh <= 1; ++kh) {
            const int hh = h + kh;
            if (hh < 0 || hh >= RESO) continue;
            #pragma unroll
            for (int kw = -1; kw <= 1; ++kw) {
                const int ww = wi + kw;
                if (ww < 0 || ww >= 8) continue;
                const int tj   = hh * 8 + ww;
                const int wofs = (kh + 1) * 3 + (kw + 1);
                #pragma unroll
                for (int dd = 0; dd < 16; ++dd) {
                    float lo, hi; unp2(Vp[tj * 16 + dd], lo, hi);
                    o[2*dd]     += cw[(2*dd)     * 9 + wofs] * lo;
                    o[2*dd + 1] += cw[(2*dd + 1) * 9 + wofs] * hi;
                }
            }
        }

        unsigned short* xo = X + ((size_t)bw * WIN + t) * DIM + head * HD;
        #pragma unroll
        for (int d = 0; d < HD; d += 8) {
            ushort4 pk, pk2;
            pk.x  = f2bf(o[d + 0]); pk.y  = f2bf(o[d + 1]);
            pk.z  = f2bf(o[d + 2]); pk.w  = f2bf(o[d + 3]);
            pk2.x = f2bf(o[d + 4]); pk2.y = f2bf(o[d + 5]);
            pk2.z = f2bf(o[d + 6]); pk2.w = f2bf(o[d + 7]);
            *(ushort4*)(xo + d)     = pk;
            *(ushort4*)(xo + d + 4) = pk2;
        }
    }
}

// ---------------------------------------------------------------------------
// Kernel 2: projection GEMM  out = X @ W^T + b, with CSwin2img permutation on
// store. Grid: 1024 blocks x 256 threads; block owns 32 tokens, thread owns
// one output channel. X tile (32x256, bf16 unpacked to fp32) in LDS, W row
// (fp32) read per-thread (L2-resident, 256KB total). Output fp32.
// ---------------------------------------------------------------------------
__global__ __launch_bounds__(256)
void proj_kernel(const unsigned short* __restrict__ X,
                 const float* __restrict__ pw,
                 const float* __restrict__ pb,
                 float* __restrict__ out)
{
    __shared__ alignas(16) float Xl[32][DIM];
    const int blk = blockIdx.x;
    const int tid = threadIdx.x;               // cout
    const size_t tokbase = (size_t)blk * 32;   // global window-token index

    for (int i = tid * 8; i < 32 * DIM; i += 256 * 8) {
        const uint4 u = *(const uint4*)&X[tokbase * DIM + i];
        float f[8];
        unp2(u.x, f[0], f[1]); unp2(u.y, f[2], f[3]);
        unp2(u.z, f[4], f[5]); unp2(u.w, f[6], f[7]);
        const int row = i >> 8, col = i & 255;
        #pragma unroll
        for (int k = 0; k < 8; ++k) Xl[row][col + k] = f[k];
    }
    __syncthreads();

    float acc[32];
    #pragma unroll
    for (int tk = 0; tk < 32; ++tk) acc[tk] = 0.f;

    for (int c0 = 0; c0 < DIM; c0 += 8) {
        const float4 w0 = *(const float4*)&pw[tid * DIM + c0];
        const float4 w1 = *(const float4*)&pw[tid * DIM + c0 + 4];
        #pragma unroll
        for (int tk = 0; tk < 32; ++tk) {
            const float4 x0 = *(const float4*)&Xl[tk][c0];
            const float4 x1 = *(const float4*)&Xl[tk][c0 + 4];
            acc[tk] += x0.x*w0.x + x0.y*w0.y + x0.z*w0.z + x0.w*w0.w
                     + x1.x*w1.x + x1.y*w1.y + x1.z*w1.z + x1.w*w1.w;
        }
    }

    const float bias = pb[tid];
    #pragma unroll
    for (int tk = 0; tk < 32; ++tk) {
        const size_t g = tokbase + tk;
        const int bw = (int)(g >> 9), t = (int)(g & 511);
        const int b = bw >> 3, wx = bw & 7, hh = t >> 3, wi = t & 7;
        // CSwin2img: out[b, h*64 + wx*8 + wi, cout]
        const size_t oofs = ((size_t)b * SEQL + (size_t)hh * RESO + wx * 8 + wi) * DIM + tid;
        out[oofs] = acc[tk] + bias;
    }
}

extern "C" void kernel_launch(void* const* d_in, const int* in_sizes, int n_in,
                              void* d_out, int out_size, void* d_ws, size_t ws_size,
                              hipStream_t stream)
{
    const float* qkv    = (const float*)d_in[0];
    const float* scale  = (const float*)d_in[1];
    const float* proj_w = (const float*)d_in[2];
    const float* proj_b = (const float*)d_in[3];
    const float* conv_w = (const float*)d_in[4];
    const float* conv_b = (const float*)d_in[5];

    unsigned short* X = (unsigned short*)d_ws;   // 64*512*256 bf16 = 16 MiB

    attn_lepe_kernel<<<dim3(BATCH * NWIN * NH), dim3(256), 0, stream>>>(
        qkv, scale, conv_w, conv_b, X);

    proj_kernel<<<dim3((BATCH * NWIN * WIN) / 32), dim3(256), 0, stream>>>(
        X, proj_w, proj_b, (float*)d_out);
}

// Round 5
// 299.385 us; speedup vs baseline: 3.3366x; 3.3366x over previous
//
#include <hip/hip_runtime.h>
#include <hip/hip_bf16.h>

// Problem constants (from reference)
#define BATCH 8
#define NH    8
#define HD    32
#define WIN   512    // 64 x 8 tokens per vertical-stripe window
#define DIM   256
#define RESO  64
#define SEQL  4096
#define VSTRIDE 520  // Vt padded token stride (bf16 elements)

typedef __attribute__((ext_vector_type(8))) short short8;   // 8 bf16 (4 VGPRs) MFMA A/B frag
typedef __attribute__((ext_vector_type(4))) float floatx4;  // MFMA C/D frag

__device__ __forceinline__ unsigned short f2bf(float f) {
    union { float f; unsigned int i; } x; x.f = f;
    unsigned int r = x.i + 0x7fff + ((x.i >> 16) & 1);   // round-to-nearest-even
    return (unsigned short)(r >> 16);
}
__device__ __forceinline__ float bf2f(unsigned short u) {
    union { unsigned int i; float f; } x; x.i = ((unsigned int)u) << 16; return x.f;
}
__device__ __forceinline__ unsigned int pk2(float lo, float hi) {
    return ((unsigned int)f2bf(hi) << 16) | (unsigned int)f2bf(lo);
}
__device__ __forceinline__ void unp2(unsigned int u, float& lo, float& hi) {
    union { unsigned int i; float f; } a, b;
    a.i = u << 16; b.i = u & 0xffff0000u;
    lo = a.f; hi = b.f;
}

union FragU {
    unsigned int  u[4];
    unsigned short us[8];
    short8        s;
    ushort4       v4[2];
};

// ---------------------------------------------------------------------------
// MFMA flash attention + LePE. Grid: 512 blocks (64 win x 8 heads) x 512 thr
// (8 waves). Wave w owns query rows w*64..w*64+63 (4 q-tiles of 16).
// S^T tiles via mfma_16x16x32 (A=K from swizzled LDS, B=Q^T from global);
// exp'd P feeds PV mfma (A=V^T frag from LDS, B=P^T DIRECT from registers —
// the C-layout of S^T equals the B-layout under a key permutation absorbed
// into the V^T fragment reads). Row sums via shfl_xor(16/32), lane-aligned
// with PV C-layout columns. Epilogue: normalize, +conv bias, LePE 3x3 from
// Vt, bf16 store to X.
// ---------------------------------------------------------------------------
__global__ __launch_bounds__(512, 4)
void attn_mfma_kernel(const float* __restrict__ qkv,
                      const float* __restrict__ scale_p,
                      const float* __restrict__ conv_w,
                      const float* __restrict__ conv_b,
                      unsigned short* __restrict__ X)
{
    __shared__ alignas(16) unsigned short Klds[WIN * HD];      // swizzled 16B chunks
    __shared__ alignas(16) unsigned short Vt[HD * VSTRIDE];    // V^T, padded
    __shared__ float cw[HD * 9];
    __shared__ float cb[HD];

    const int wh   = blockIdx.x;
    const int bw   = wh >> 3;        // global window 0..63
    const int head = wh & 7;
    const int b    = bw >> 3;
    const int wx   = bw & 7;
    const int tid  = threadIdx.x;

    const float scale = scale_p[0];
    const size_t plane = (size_t)BATCH * SEQL * DIM;
    const float* qg = qkv;
    const float* kg = qkv + plane;
    const float* vg = qkv + 2 * plane;

    // ---- Stage K (bf16, XOR-swizzled 16B chunks) ----
    for (int idx = tid; idx < WIN * 4; idx += 512) {
        const int t = idx >> 2, c8 = idx & 3;
        const size_t goff = ((size_t)b * SEQL + (size_t)(t >> 3) * RESO + wx * 8 + (t & 7)) * DIM
                          + head * HD + c8 * 8;
        const float4 k0 = *(const float4*)(kg + goff);
        const float4 k1 = *(const float4*)(kg + goff + 4);
        uint4 pk;
        pk.x = pk2(k0.x, k0.y); pk.y = pk2(k0.z, k0.w);
        pk.z = pk2(k1.x, k1.y); pk.w = pk2(k1.z, k1.w);
        const int p = c8 ^ ((t >> 1) & 3);
        *(uint4*)&Klds[t * HD + p * 8] = pk;
    }
    // ---- Stage V^T (bf16, padded stride; token pairs packed as b32) ----
    for (int idx = tid; idx < 256 * HD; idx += 512) {
        const int ch = idx & 31, tp = idx >> 5;
        const int t = tp * 2;
        const size_t goff = ((size_t)b * SEQL + (size_t)(t >> 3) * RESO + wx * 8 + (t & 7)) * DIM
                          + head * HD + ch;
        const float v0 = vg[goff];
        const float v1 = vg[goff + DIM];       // token t+1 (same image row)
        *(unsigned int*)&Vt[ch * VSTRIDE + t] = pk2(v0, v1);
    }
    for (int i = tid; i < HD * 9; i += 512) cw[i] = conv_w[head * HD * 9 + i];
    if (tid < HD) cb[tid] = conv_b[head * HD + tid];
    __syncthreads();

    const int lane = tid & 63, wid = tid >> 6;
    const int q4 = lane >> 4, nn = lane & 15;
    const int qbase = wid * 64;

    // mask add (only stripe wx==7): key group vs query group, lane-constant
    float mk[4];
    #pragma unroll
    for (int r = 0; r < 4; ++r) {
        const bool kgrp = (((q4 * 4 + r) & 7) < 4);
        const bool qgrp = ((nn & 7) < 4);
        mk[r] = (wx == 7 && (kgrp != qgrp)) ? -100.f : 0.f;
    }

    // ---- Q B-frags (4 q-tiles), pre-scaled, bf16 ----
    short8 qf[4];
    #pragma unroll
    for (int qq = 0; qq < 4; ++qq) {
        const int t = qbase + qq * 16 + nn;
        const size_t goff = ((size_t)b * SEQL + (size_t)(t >> 3) * RESO + wx * 8 + (t & 7)) * DIM
                          + head * HD + q4 * 8;
        const float4 a = *(const float4*)(qg + goff);
        const float4 c = *(const float4*)(qg + goff + 4);
        FragU f;
        f.u[0] = pk2(a.x * scale, a.y * scale);
        f.u[1] = pk2(a.z * scale, a.w * scale);
        f.u[2] = pk2(c.x * scale, c.y * scale);
        f.u[3] = pk2(c.z * scale, c.w * scale);
        qf[qq] = f.s;
    }

    floatx4 acc[4][2];
    #pragma unroll
    for (int qq = 0; qq < 4; ++qq) {
        acc[qq][0] = (floatx4){0.f, 0.f, 0.f, 0.f};
        acc[qq][1] = (floatx4){0.f, 0.f, 0.f, 0.f};
    }
    float rs[4] = {0.f, 0.f, 0.f, 0.f};
    const floatx4 zf = (floatx4){0.f, 0.f, 0.f, 0.f};

    // ---- main K loop: 16 chunks of 32 keys (2 j-tiles each) ----
    for (int kc = 0; kc < 16; ++kc) {
        // K A-frags for the two 16-key tiles (swizzled chunk read, b128)
        short8 kf0, kf1;
        {
            const int t0 = (2 * kc) * 16 + nn;
            const int t1 = (2 * kc + 1) * 16 + nn;
            kf0 = *(const short8*)&Klds[t0 * HD + (q4 ^ ((t0 >> 1) & 3)) * 8];
            kf1 = *(const short8*)&Klds[t1 * HD + (q4 ^ ((t1 >> 1) & 3)) * 8];
        }
        // V^T A-frags (key-permuted: two 4-token runs per lane)
        short8 vf[2];
        #pragma unroll
        for (int nt = 0; nt < 2; ++nt) {
            const int ch = nt * 16 + nn;
            FragU f;
            f.v4[0] = *(const ushort4*)&Vt[ch * VSTRIDE + kc * 32 + q4 * 4];
            f.v4[1] = *(const ushort4*)&Vt[ch * VSTRIDE + kc * 32 + 16 + q4 * 4];
            vf[nt] = f.s;
        }
        #pragma unroll
        for (int qq = 0; qq < 4; ++qq) {
            floatx4 s0 = __builtin_amdgcn_mfma_f32_16x16x32_bf16(kf0, qf[qq], zf, 0, 0, 0);
            floatx4 s1 = __builtin_amdgcn_mfma_f32_16x16x32_bf16(kf1, qf[qq], zf, 0, 0, 0);
            float p[8];
            #pragma unroll
            for (int r = 0; r < 4; ++r) {
                p[r]     = __expf(s0[r] + mk[r]);
                p[4 + r] = __expf(s1[r] + mk[r]);
            }
            rs[qq] += ((p[0] + p[1]) + (p[2] + p[3])) + ((p[4] + p[5]) + (p[6] + p[7]));
            FragU pf;
            pf.u[0] = pk2(p[0], p[1]);
            pf.u[1] = pk2(p[2], p[3]);
            pf.u[2] = pk2(p[4], p[5]);
            pf.u[3] = pk2(p[6], p[7]);
            acc[qq][0] = __builtin_amdgcn_mfma_f32_16x16x32_bf16(vf[0], pf.s, acc[qq][0], 0, 0, 0);
            acc[qq][1] = __builtin_amdgcn_mfma_f32_16x16x32_bf16(vf[1], pf.s, acc[qq][1], 0, 0, 0);
        }
    }

    // ---- row sums: reduce across the 4 quads; lane-aligned with PV cols ----
    float inv[4];
    #pragma unroll
    for (int qq = 0; qq < 4; ++qq) {
        float v = rs[qq];
        v += __shfl_xor(v, 16);
        v += __shfl_xor(v, 32);
        inv[qq] = 1.0f / v;
    }

    // ---- epilogue: normalize, +conv bias, LePE 3x3 from Vt, store bf16 X ----
    #pragma unroll
    for (int qq = 0; qq < 4; ++qq) {
        const int t = qbase + qq * 16 + nn;
        const int h = t >> 3, wi = t & 7;
        #pragma unroll
        for (int nt = 0; nt < 2; ++nt) {
            const int chb = nt * 16 + q4 * 4;
            float o[4];
            #pragma unroll
            for (int r = 0; r < 4; ++r)
                o[r] = acc[qq][nt][r] * inv[qq] + cb[chb + r];
            #pragma unroll
            for (int dh = -1; dh <= 1; ++dh) {
                const int hh = h + dh;
                if (hh < 0 || hh >= RESO) continue;
                #pragma unroll
                for (int dw = -1; dw <= 1; ++dw) {
                    const int ww = wi + dw;
                    if (ww < 0 || ww >= 8) continue;
                    const int tj  = hh * 8 + ww;
                    const int wof = (dh + 1) * 3 + (dw + 1);
                    #pragma unroll
                    for (int r = 0; r < 4; ++r)
                        o[r] += cw[(chb + r) * 9 + wof] * bf2f(Vt[(chb + r) * VSTRIDE + tj]);
                }
            }
            ushort4 st;
            st.x = f2bf(o[0]); st.y = f2bf(o[1]); st.z = f2bf(o[2]); st.w = f2bf(o[3]);
            *(ushort4*)&X[((size_t)bw * WIN + t) * DIM + head * HD + chb] = st;
        }
    }
}

// ---------------------------------------------------------------------------
// Kernel 2: projection GEMM  out = X @ W^T + b, CSwin2img permutation on
// store (unchanged from round 4 — passed). Output fp32.
// ---------------------------------------------------------------------------
__global__ __launch_bounds__(256)
void proj_kernel(const unsigned short* __restrict__ X,
                 const float* __restrict__ pw,
                 const float* __restrict__ pb,
                 float* __restrict__ out)
{
    __shared__ alignas(16) float Xl[32][DIM];
    const int blk = blockIdx.x;
    const int tid = threadIdx.x;               // cout
    const size_t tokbase = (size_t)blk * 32;   // global window-token index

    for (int i = tid * 8; i < 32 * DIM; i += 256 * 8) {
        const uint4 u = *(const uint4*)&X[tokbase * DIM + i];
        float f[8];
        unp2(u.x, f[0], f[1]); unp2(u.y, f[2], f[3]);
        unp2(u.z, f[4], f[5]); unp2(u.w, f[6], f[7]);
        const int row = i >> 8, col = i & 255;
        #pragma unroll
        for (int k = 0; k < 8; ++k) Xl[row][col + k] = f[k];
    }
    __syncthreads();

    float acc[32];
    #pragma unroll
    for (int tk = 0; tk < 32; ++tk) acc[tk] = 0.f;

    for (int c0 = 0; c0 < DIM; c0 += 8) {
        const float4 w0 = *(const float4*)&pw[tid * DIM + c0];
        const float4 w1 = *(const float4*)&pw[tid * DIM + c0 + 4];
        #pragma unroll
        for (int tk = 0; tk < 32; ++tk) {
            const float4 x0 = *(const float4*)&Xl[tk][c0];
            const float4 x1 = *(const float4*)&Xl[tk][c0 + 4];
            acc[tk] += x0.x*w0.x + x0.y*w0.y + x0.z*w0.z + x0.w*w0.w
                     + x1.x*w1.x + x1.y*w1.y + x1.z*w1.z + x1.w*w1.w;
        }
    }

    const float bias = pb[tid];
    #pragma unroll
    for (int tk = 0; tk < 32; ++tk) {
        const size_t g = tokbase + tk;
        const int bw = (int)(g >> 9), t = (int)(g & 511);
        const int b = bw >> 3, wx = bw & 7, hh = t >> 3, wi = t & 7;
        const size_t oofs = ((size_t)b * SEQL + (size_t)hh * RESO + wx * 8 + wi) * DIM + tid;
        out[oofs] = acc[tk] + bias;
    }
}

extern "C" void kernel_launch(void* const* d_in, const int* in_sizes, int n_in,
                              void* d_out, int out_size, void* d_ws, size_t ws_size,
                              hipStream_t stream)
{
    const float* qkv    = (const float*)d_in[0];
    const float* scale  = (const float*)d_in[1];
    const float* proj_w = (const float*)d_in[2];
    const float* proj_b = (const float*)d_in[3];
    const float* conv_w = (const float*)d_in[4];
    const float* conv_b = (const float*)d_in[5];

    unsigned short* X = (unsigned short*)d_ws;   // 64*512*256 bf16 = 16 MiB

    attn_mfma_kernel<<<dim3(BATCH * NH * 8), dim3(512), 0, stream>>>(
        qkv, scale, conv_w, conv_b, X);

    proj_kernel<<<dim3((BATCH * 8 * WIN) / 32), dim3(256), 0, stream>>>(
        X, proj_w, proj_b, (float*)d_out);
}

// Round 6
// 220.033 us; speedup vs baseline: 4.5399x; 1.3606x over previous
//
#include <hip/hip_runtime.h>
#include <hip/hip_bf16.h>

// Problem constants (from reference)
#define BATCH 8
#define NH    8
#define HD    32
#define WIN   512    // 64 x 8 tokens per vertical-stripe window
#define DIM   256
#define RESO  64
#define SEQL  4096
#define VSTRIDE 520  // Vt padded token stride (bf16 elements)
#define WPAD  264    // proj W LDS row stride (bf16 elements)

typedef __attribute__((ext_vector_type(8))) short short8;   // 8 bf16 (4 VGPRs) MFMA A/B frag
typedef __attribute__((ext_vector_type(4))) float floatx4;  // MFMA C/D frag

__device__ __forceinline__ unsigned short f2bf(float f) {
    union { float f; unsigned int i; } x; x.f = f;
    unsigned int r = x.i + 0x7fff + ((x.i >> 16) & 1);   // round-to-nearest-even
    return (unsigned short)(r >> 16);
}
__device__ __forceinline__ float bf2f(unsigned short u) {
    union { unsigned int i; float f; } x; x.i = ((unsigned int)u) << 16; return x.f;
}
__device__ __forceinline__ unsigned int pk2(float lo, float hi) {      // RNE pack
    return ((unsigned int)f2bf(hi) << 16) | (unsigned int)f2bf(lo);
}
__device__ __forceinline__ unsigned int pk2t(float lo, float hi) {     // truncation pack, 1 v_perm
    union { float f; unsigned int i; } a, b; a.f = lo; b.f = hi;
    return __builtin_amdgcn_perm(b.i, a.i, 0x07060302);                // {hi[3],hi[2],lo[3],lo[2]}
}
__device__ __forceinline__ void unp2(unsigned int u, float& lo, float& hi) {
    union { unsigned int i; float f; } a, b;
    a.i = u << 16; b.i = u & 0xffff0000u;
    lo = a.f; hi = b.f;
}

union FragU {
    unsigned int  u[4];
    unsigned short us[8];
    short8        s;
    ushort4       v4[2];
};

// ---------------------------------------------------------------------------
// MFMA flash attention + LePE. Grid: 512 blocks (64 win x 8 heads) x 512 thr
// (8 waves). Wave w owns query rows w*64..w*64+63 (4 q-tiles of 16).
// S^T tiles via mfma_16x16x32 (A=K from swizzled LDS, B=Q^T from global);
// exp'd P feeds PV mfma directly from registers (S^T C-layout == B-layout
// under the key permutation absorbed into the V^T fragment reads).
// ---------------------------------------------------------------------------
__global__ __launch_bounds__(512, 4)
void attn_mfma_kernel(const float* __restrict__ qkv,
                      const float* __restrict__ scale_p,
                      const float* __restrict__ conv_w,
                      const float* __restrict__ conv_b,
                      unsigned short* __restrict__ X)
{
    __shared__ alignas(16) unsigned short Klds[WIN * HD];      // swizzled 16B chunks
    __shared__ alignas(16) unsigned short Vt[HD * VSTRIDE];    // V^T, padded
    __shared__ float cw[HD * 9];
    __shared__ float cb[HD];

    const int wh   = blockIdx.x;
    const int bw   = wh >> 3;        // global window 0..63
    const int head = wh & 7;
    const int b    = bw >> 3;
    const int wx   = bw & 7;
    const int tid  = threadIdx.x;

    const float scale = scale_p[0];
    const size_t plane = (size_t)BATCH * SEQL * DIM;
    const float* qg = qkv;
    const float* kg = qkv + plane;
    const float* vg = qkv + 2 * plane;

    // ---- Stage K (bf16 RNE, XOR-swizzled 16B chunks) ----
    for (int idx = tid; idx < WIN * 4; idx += 512) {
        const int t = idx >> 2, c8 = idx & 3;
        const size_t goff = ((size_t)b * SEQL + (size_t)(t >> 3) * RESO + wx * 8 + (t & 7)) * DIM
                          + head * HD + c8 * 8;
        const float4 k0 = *(const float4*)(kg + goff);
        const float4 k1 = *(const float4*)(kg + goff + 4);
        uint4 pk;
        pk.x = pk2(k0.x, k0.y); pk.y = pk2(k0.z, k0.w);
        pk.z = pk2(k1.x, k1.y); pk.w = pk2(k1.z, k1.w);
        const int p = c8 ^ ((t >> 1) & 3);
        *(uint4*)&Klds[t * HD + p * 8] = pk;
    }
    // ---- Stage V^T (bf16 RNE, padded stride; token pairs packed as b32) ----
    for (int idx = tid; idx < 256 * HD; idx += 512) {
        const int ch = idx & 31, tp = idx >> 5;
        const int t = tp * 2;
        const size_t goff = ((size_t)b * SEQL + (size_t)(t >> 3) * RESO + wx * 8 + (t & 7)) * DIM
                          + head * HD + ch;
        const float v0 = vg[goff];
        const float v1 = vg[goff + DIM];       // token t+1 (same image row)
        *(unsigned int*)&Vt[ch * VSTRIDE + t] = pk2(v0, v1);
    }
    for (int i = tid; i < HD * 9; i += 512) cw[i] = conv_w[head * HD * 9 + i];
    if (tid < HD) cb[tid] = conv_b[head * HD + tid];
    __syncthreads();

    const int lane = tid & 63, wid = tid >> 6;
    const int q4 = lane >> 4, nn = lane & 15;
    const int qbase = wid * 64;

    // mask add (only stripe wx==7): key group vs query group, lane-constant
    float mk[4];
    #pragma unroll
    for (int r = 0; r < 4; ++r) {
        const bool kgrp = (((q4 * 4 + r) & 7) < 4);
        const bool qgrp = ((nn & 7) < 4);
        mk[r] = (wx == 7 && (kgrp != qgrp)) ? -100.f : 0.f;
    }

    // ---- Q B-frags (4 q-tiles), pre-scaled, bf16 ----
    short8 qf[4];
    #pragma unroll
    for (int qq = 0; qq < 4; ++qq) {
        const int t = qbase + qq * 16 + nn;
        const size_t goff = ((size_t)b * SEQL + (size_t)(t >> 3) * RESO + wx * 8 + (t & 7)) * DIM
                          + head * HD + q4 * 8;
        const float4 a = *(const float4*)(qg + goff);
        const float4 c = *(const float4*)(qg + goff + 4);
        FragU f;
        f.u[0] = pk2(a.x * scale, a.y * scale);
        f.u[1] = pk2(a.z * scale, a.w * scale);
        f.u[2] = pk2(c.x * scale, c.y * scale);
        f.u[3] = pk2(c.z * scale, c.w * scale);
        qf[qq] = f.s;
    }

    floatx4 acc[4][2];
    #pragma unroll
    for (int qq = 0; qq < 4; ++qq) {
        acc[qq][0] = (floatx4){0.f, 0.f, 0.f, 0.f};
        acc[qq][1] = (floatx4){0.f, 0.f, 0.f, 0.f};
    }
    float rs[4] = {0.f, 0.f, 0.f, 0.f};
    const floatx4 zf = (floatx4){0.f, 0.f, 0.f, 0.f};

    // ---- main K loop: 16 chunks of 32 keys (2 j-tiles each) ----
    for (int kc = 0; kc < 16; ++kc) {
        short8 kf0, kf1;
        {
            const int t0 = (2 * kc) * 16 + nn;
            const int t1 = (2 * kc + 1) * 16 + nn;
            kf0 = *(const short8*)&Klds[t0 * HD + (q4 ^ ((t0 >> 1) & 3)) * 8];
            kf1 = *(const short8*)&Klds[t1 * HD + (q4 ^ ((t1 >> 1) & 3)) * 8];
        }
        short8 vf[2];
        #pragma unroll
        for (int nt = 0; nt < 2; ++nt) {
            const int ch = nt * 16 + nn;
            FragU f;
            f.v4[0] = *(const ushort4*)&Vt[ch * VSTRIDE + kc * 32 + q4 * 4];
            f.v4[1] = *(const ushort4*)&Vt[ch * VSTRIDE + kc * 32 + 16 + q4 * 4];
            vf[nt] = f.s;
        }
        #pragma unroll
        for (int qq = 0; qq < 4; ++qq) {
            floatx4 s0 = __builtin_amdgcn_mfma_f32_16x16x32_bf16(kf0, qf[qq], zf, 0, 0, 0);
            floatx4 s1 = __builtin_amdgcn_mfma_f32_16x16x32_bf16(kf1, qf[qq], zf, 0, 0, 0);
            float p[8];
            #pragma unroll
            for (int r = 0; r < 4; ++r) {
                p[r]     = __expf(s0[r] + mk[r]);
                p[4 + r] = __expf(s1[r] + mk[r]);
            }
            rs[qq] += ((p[0] + p[1]) + (p[2] + p[3])) + ((p[4] + p[5]) + (p[6] + p[7]));
            FragU pf;                                    // truncation pack: 1 v_perm each
            pf.u[0] = pk2t(p[0], p[1]);
            pf.u[1] = pk2t(p[2], p[3]);
            pf.u[2] = pk2t(p[4], p[5]);
            pf.u[3] = pk2t(p[6], p[7]);
            acc[qq][0] = __builtin_amdgcn_mfma_f32_16x16x32_bf16(vf[0], pf.s, acc[qq][0], 0, 0, 0);
            acc[qq][1] = __builtin_amdgcn_mfma_f32_16x16x32_bf16(vf[1], pf.s, acc[qq][1], 0, 0, 0);
        }
    }

    // ---- row sums across quads; lane-aligned with PV C-layout columns ----
    float inv[4];
    #pragma unroll
    for (int qq = 0; qq < 4; ++qq) {
        float v = rs[qq];
        v += __shfl_xor(v, 16);
        v += __shfl_xor(v, 32);
        inv[qq] = 1.0f / v;
    }

    // ---- epilogue: normalize, +conv bias, LePE 3x3 from Vt, store bf16 X ----
    #pragma unroll
    for (int qq = 0; qq < 4; ++qq) {
        const int t = qbase + qq * 16 + nn;
        const int h = t >> 3, wi = t & 7;
        #pragma unroll
        for (int nt = 0; nt < 2; ++nt) {
            const int chb = nt * 16 + q4 * 4;
            float o[4];
            #pragma unroll
            for (int r = 0; r < 4; ++r)
                o[r] = acc[qq][nt][r] * inv[qq] + cb[chb + r];
            #pragma unroll
            for (int dh = -1; dh <= 1; ++dh) {
                const int hh = h + dh;
                if (hh < 0 || hh >= RESO) continue;
                #pragma unroll
                for (int dw = -1; dw <= 1; ++dw) {
                    const int ww = wi + dw;
                    if (ww < 0 || ww >= 8) continue;
                    const int tj  = hh * 8 + ww;
                    const int wof = (dh + 1) * 3 + (dw + 1);
                    #pragma unroll
                    for (int r = 0; r < 4; ++r)
                        o[r] += cw[(chb + r) * 9 + wof] * bf2f(Vt[(chb + r) * VSTRIDE + tj]);
                }
            }
            ushort4 st;
            st.x = f2bf(o[0]); st.y = f2bf(o[1]); st.z = f2bf(o[2]); st.w = f2bf(o[3]);
            *(ushort4*)&X[((size_t)bw * WIN + t) * DIM + head * HD + chb] = st;
        }
    }
}

// ---------------------------------------------------------------------------
// Kernel 2: MFMA projection GEMM  out = X @ W^T + b, CSwin2img permuted rows.
// Grid: 512 blocks (128 m-blocks x 4 n-blocks) x 256 thr (4 waves).
// Block stages its 64x256 W slice fp32->bf16 (RNE) into padded LDS once;
// wave computes D = W . X^T (A=W from LDS, B=X^T from global bf16 ws):
// n lands on the reg axis -> contiguous float4 (bias+store) per lane.
// ---------------------------------------------------------------------------
__global__ __launch_bounds__(256, 4)
void proj_mfma_kernel(const unsigned short* __restrict__ X,
                      const float* __restrict__ pw,
                      const float* __restrict__ pb,
                      float* __restrict__ out)
{
    __shared__ alignas(16) unsigned short Wl[64 * WPAD];   // 33.8 KB

    const int bx   = blockIdx.x;
    const int mblk = bx >> 2;            // 0..127 -> 256 tokens each
    const int nblk = bx & 3;             // 0..3   -> 64 channels each
    const int tid  = threadIdx.x;
    const int n0   = nblk * 64;

    // ---- stage W[n0..n0+63][0..255] -> bf16 LDS (4 threads per row) ----
    {
        const int row = tid >> 2;
        const int cb0 = (tid & 3) * 64;
        #pragma unroll
        for (int c = 0; c < 64; c += 8) {
            const float4 w0 = *(const float4*)&pw[(size_t)(n0 + row) * DIM + cb0 + c];
            const float4 w1 = *(const float4*)&pw[(size_t)(n0 + row) * DIM + cb0 + c + 4];
            uint4 pk;
            pk.x = pk2(w0.x, w0.y); pk.y = pk2(w0.z, w0.w);
            pk.z = pk2(w1.x, w1.y); pk.w = pk2(w1.z, w1.w);
            *(uint4*)&Wl[row * WPAD + cb0 + c] = pk;
        }
    }
    __syncthreads();

    const int lane = tid & 63, wid = tid >> 6;
    const int q4 = lane >> 4, nn = lane & 15;
    const int mwave = mblk * 256 + wid * 64;     // 64 tokens per wave

    floatx4 acc[4][4];                            // [nt][mt]
    #pragma unroll
    for (int i = 0; i < 4; ++i)
        #pragma unroll
        for (int j = 0; j < 4; ++j)
            acc[i][j] = (floatx4){0.f, 0.f, 0.f, 0.f};

    for (int kk = 0; kk < 8; ++kk) {
        short8 af[4], bf[4];
        #pragma unroll
        for (int nt = 0; nt < 4; ++nt)
            af[nt] = *(const short8*)&Wl[(nt * 16 + nn) * WPAD + kk * 32 + q4 * 8];
        #pragma unroll
        for (int mt = 0; mt < 4; ++mt) {
            const int m = mwave + mt * 16 + nn;
            bf[mt] = *(const short8*)&X[(size_t)m * DIM + kk * 32 + q4 * 8];
        }
        #pragma unroll
        for (int nt = 0; nt < 4; ++nt)
            #pragma unroll
            for (int mt = 0; mt < 4; ++mt)
                acc[nt][mt] = __builtin_amdgcn_mfma_f32_16x16x32_bf16(af[nt], bf[mt], acc[nt][mt], 0, 0, 0);
    }

    // ---- bias + permuted store (float4 per lane per tile) ----
    float4 bias[4];
    #pragma unroll
    for (int nt = 0; nt < 4; ++nt)
        bias[nt] = *(const float4*)&pb[n0 + nt * 16 + q4 * 4];

    size_t rowoff[4];
    #pragma unroll
    for (int mt = 0; mt < 4; ++mt) {
        const int m  = mwave + mt * 16 + nn;
        const int bw = m >> 9, t = m & 511;
        const int bb = bw >> 3, wx = bw & 7, hh = t >> 3, wi = t & 7;
        rowoff[mt] = ((size_t)bb * SEQL + (size_t)hh * RESO + wx * 8 + wi) * DIM;
    }

    #pragma unroll
    for (int nt = 0; nt < 4; ++nt)
        #pragma unroll
        for (int mt = 0; mt < 4; ++mt) {
            float4 v;
            v.x = acc[nt][mt][0] + bias[nt].x;
            v.y = acc[nt][mt][1] + bias[nt].y;
            v.z = acc[nt][mt][2] + bias[nt].z;
            v.w = acc[nt][mt][3] + bias[nt].w;
            *(float4*)&out[rowoff[mt] + n0 + nt * 16 + q4 * 4] = v;
        }
}

extern "C" void kernel_launch(void* const* d_in, const int* in_sizes, int n_in,
                              void* d_out, int out_size, void* d_ws, size_t ws_size,
                              hipStream_t stream)
{
    const float* qkv    = (const float*)d_in[0];
    const float* scale  = (const float*)d_in[1];
    const float* proj_w = (const float*)d_in[2];
    const float* proj_b = (const float*)d_in[3];
    const float* conv_w = (const float*)d_in[4];
    const float* conv_b = (const float*)d_in[5];

    unsigned short* X = (unsigned short*)d_ws;   // 64*512*256 bf16 = 16 MiB

    attn_mfma_kernel<<<dim3(BATCH * NH * 8), dim3(512), 0, stream>>>(
        qkv, scale, conv_w, conv_b, X);

    proj_mfma_kernel<<<dim3(512), dim3(256), 0, stream>>>(
        X, proj_w, proj_b, (float*)d_out);
}

// Round 7
// 213.521 us; speedup vs baseline: 4.6784x; 1.0305x over previous
//
#include <hip/hip_runtime.h>
#include <hip/hip_bf16.h>

// Problem constants (from reference)
#define BATCH 8
#define NH    8
#define HD    32
#define WIN   512    // 64 x 8 tokens per vertical-stripe window
#define DIM   256
#define RESO  64
#define SEQL  4096
#define VSTRIDE 520  // Vt padded token stride (bf16 elements)
#define WPAD  264    // proj W LDS row stride (bf16 elements)

#define LOG2E 1.44269504088896340736f

extern "C" __device__ float __ocml_native_exp2_f32(float);   // raw v_exp_f32

typedef __attribute__((ext_vector_type(8))) short short8;   // 8 bf16 (4 VGPRs) MFMA A/B frag
typedef __attribute__((ext_vector_type(4))) float floatx4;  // MFMA C/D frag

__device__ __forceinline__ unsigned short f2bf(float f) {
    union { float f; unsigned int i; } x; x.f = f;
    unsigned int r = x.i + 0x7fff + ((x.i >> 16) & 1);   // round-to-nearest-even
    return (unsigned short)(r >> 16);
}
__device__ __forceinline__ float bf2f(unsigned short u) {
    union { unsigned int i; float f; } x; x.i = ((unsigned int)u) << 16; return x.f;
}
__device__ __forceinline__ unsigned int pk2(float lo, float hi) {      // RNE pack
    return ((unsigned int)f2bf(hi) << 16) | (unsigned int)f2bf(lo);
}
__device__ __forceinline__ unsigned int pk2t(float lo, float hi) {     // truncation pack, 1 v_perm
    union { float f; unsigned int i; } a, b; a.f = lo; b.f = hi;
    return __builtin_amdgcn_perm(b.i, a.i, 0x07060302);                // {hi[3],hi[2],lo[3],lo[2]}
}
__device__ __forceinline__ void unp2(unsigned int u, float& lo, float& hi) {
    union { unsigned int i; float f; } a, b;
    a.i = u << 16; b.i = u & 0xffff0000u;
    lo = a.f; hi = b.f;
}

union FragU {
    unsigned int  u[4];
    unsigned short us[8];
    short8        s;
    ushort4       v4[2];
};

// ---------------------------------------------------------------------------
// MFMA flash attention + LePE. Grid: 512 blocks (64 win x 8 heads) x 512 thr
// (8 waves). Wave w owns query rows w*64..w*64+63 (4 q-tiles of 16).
// Q pre-scaled by scale*log2e -> scores arrive in log2 domain; p = v_exp_f32.
// S^T tiles via mfma_16x16x32 (A=K from swizzled LDS, B=Q^T from global);
// exp'd P feeds PV mfma directly from registers (S^T C-layout == B-layout
// under the key permutation absorbed into the V^T fragment reads).
// ---------------------------------------------------------------------------
__global__ __launch_bounds__(512, 4)
void attn_mfma_kernel(const float* __restrict__ qkv,
                      const float* __restrict__ scale_p,
                      const float* __restrict__ conv_w,
                      const float* __restrict__ conv_b,
                      unsigned short* __restrict__ X)
{
    __shared__ alignas(16) unsigned short Klds[WIN * HD];      // swizzled 16B chunks
    __shared__ alignas(16) unsigned short Vt[HD * VSTRIDE];    // V^T, padded
    __shared__ float cw[HD * 9];
    __shared__ float cb[HD];

    const int wh   = blockIdx.x;
    const int bw   = wh >> 3;        // global window 0..63
    const int head = wh & 7;
    const int b    = bw >> 3;
    const int wx   = bw & 7;
    const int tid  = threadIdx.x;

    const float scale = scale_p[0] * LOG2E;    // log2-domain logits
    const size_t plane = (size_t)BATCH * SEQL * DIM;
    const float* qg = qkv;
    const float* kg = qkv + plane;
    const float* vg = qkv + 2 * plane;

    // ---- Stage K (bf16 trunc, XOR-swizzled 16B chunks) ----
    for (int idx = tid; idx < WIN * 4; idx += 512) {
        const int t = idx >> 2, c8 = idx & 3;
        const size_t goff = ((size_t)b * SEQL + (size_t)(t >> 3) * RESO + wx * 8 + (t & 7)) * DIM
                          + head * HD + c8 * 8;
        const float4 k0 = *(const float4*)(kg + goff);
        const float4 k1 = *(const float4*)(kg + goff + 4);
        uint4 pk;
        pk.x = pk2t(k0.x, k0.y); pk.y = pk2t(k0.z, k0.w);
        pk.z = pk2t(k1.x, k1.y); pk.w = pk2t(k1.z, k1.w);
        const int p = c8 ^ ((t >> 1) & 3);
        *(uint4*)&Klds[t * HD + p * 8] = pk;
    }
    // ---- Stage V^T (bf16 RNE, padded stride; token pairs packed as b32) ----
    for (int idx = tid; idx < 256 * HD; idx += 512) {
        const int ch = idx & 31, tp = idx >> 5;
        const int t = tp * 2;
        const size_t goff = ((size_t)b * SEQL + (size_t)(t >> 3) * RESO + wx * 8 + (t & 7)) * DIM
                          + head * HD + ch;
        const float v0 = vg[goff];
        const float v1 = vg[goff + DIM];       // token t+1 (same image row)
        *(unsigned int*)&Vt[ch * VSTRIDE + t] = pk2(v0, v1);
    }
    for (int i = tid; i < HD * 9; i += 512) cw[i] = conv_w[head * HD * 9 + i];
    if (tid < HD) cb[tid] = conv_b[head * HD + tid];
    __syncthreads();

    const int lane = tid & 63, wid = tid >> 6;
    const int q4 = lane >> 4, nn = lane & 15;
    const int qbase = wid * 64;
    const bool mwin = (wx == 7);

    // mask add (only stripe wx==7): key group vs query group, lane-constant
    float mk[4];
    #pragma unroll
    for (int r = 0; r < 4; ++r) {
        const bool kgrp = (((q4 * 4 + r) & 7) < 4);
        const bool qgrp = ((nn & 7) < 4);
        mk[r] = (kgrp != qgrp) ? (-100.f * LOG2E) : 0.f;
    }

    // ---- Q B-frags (4 q-tiles), pre-scaled (log2e folded), bf16 trunc ----
    short8 qf[4];
    #pragma unroll
    for (int qq = 0; qq < 4; ++qq) {
        const int t = qbase + qq * 16 + nn;
        const size_t goff = ((size_t)b * SEQL + (size_t)(t >> 3) * RESO + wx * 8 + (t & 7)) * DIM
                          + head * HD + q4 * 8;
        const float4 a = *(const float4*)(qg + goff);
        const float4 c = *(const float4*)(qg + goff + 4);
        FragU f;
        f.u[0] = pk2t(a.x * scale, a.y * scale);
        f.u[1] = pk2t(a.z * scale, a.w * scale);
        f.u[2] = pk2t(c.x * scale, c.y * scale);
        f.u[3] = pk2t(c.z * scale, c.w * scale);
        qf[qq] = f.s;
    }

    floatx4 acc[4][2];
    #pragma unroll
    for (int qq = 0; qq < 4; ++qq) {
        acc[qq][0] = (floatx4){0.f, 0.f, 0.f, 0.f};
        acc[qq][1] = (floatx4){0.f, 0.f, 0.f, 0.f};
    }
    float rs[4] = {0.f, 0.f, 0.f, 0.f};
    const floatx4 zf = (floatx4){0.f, 0.f, 0.f, 0.f};

    // ---- main K loop: 16 chunks of 32 keys (2 j-tiles each) ----
    for (int kc = 0; kc < 16; ++kc) {
        short8 kf0, kf1;
        {
            const int t0 = (2 * kc) * 16 + nn;
            const int t1 = (2 * kc + 1) * 16 + nn;
            kf0 = *(const short8*)&Klds[t0 * HD + (q4 ^ ((t0 >> 1) & 3)) * 8];
            kf1 = *(const short8*)&Klds[t1 * HD + (q4 ^ ((t1 >> 1) & 3)) * 8];
        }
        short8 vf[2];
        #pragma unroll
        for (int nt = 0; nt < 2; ++nt) {
            const int ch = nt * 16 + nn;
            FragU f;
            f.v4[0] = *(const ushort4*)&Vt[ch * VSTRIDE + kc * 32 + q4 * 4];
            f.v4[1] = *(const ushort4*)&Vt[ch * VSTRIDE + kc * 32 + 16 + q4 * 4];
            vf[nt] = f.s;
        }
        #pragma unroll
        for (int qq = 0; qq < 4; ++qq) {
            floatx4 s0 = __builtin_amdgcn_mfma_f32_16x16x32_bf16(kf0, qf[qq], zf, 0, 0, 0);
            floatx4 s1 = __builtin_amdgcn_mfma_f32_16x16x32_bf16(kf1, qf[qq], zf, 0, 0, 0);
            if (mwin) {                              // wave-uniform branch (1/8 blocks)
                #pragma unroll
                for (int r = 0; r < 4; ++r) { s0[r] += mk[r]; s1[r] += mk[r]; }
            }
            float p[8];
            #pragma unroll
            for (int r = 0; r < 4; ++r) {
                p[r]     = __ocml_native_exp2_f32(s0[r]);   // single v_exp_f32
                p[4 + r] = __ocml_native_exp2_f32(s1[r]);
            }
            rs[qq] += ((p[0] + p[1]) + (p[2] + p[3])) + ((p[4] + p[5]) + (p[6] + p[7]));
            FragU pf;                                // truncation pack: 1 v_perm each
            pf.u[0] = pk2t(p[0], p[1]);
            pf.u[1] = pk2t(p[2], p[3]);
            pf.u[2] = pk2t(p[4], p[5]);
            pf.u[3] = pk2t(p[6], p[7]);
            acc[qq][0] = __builtin_amdgcn_mfma_f32_16x16x32_bf16(vf[0], pf.s, acc[qq][0], 0, 0, 0);
            acc[qq][1] = __builtin_amdgcn_mfma_f32_16x16x32_bf16(vf[1], pf.s, acc[qq][1], 0, 0, 0);
        }
    }

    // ---- row sums across quads; lane-aligned with PV C-layout columns ----
    float inv[4];
    #pragma unroll
    for (int qq = 0; qq < 4; ++qq) {
        float v = rs[qq];
        v += __shfl_xor(v, 16);
        v += __shfl_xor(v, 32);
        inv[qq] = 1.0f / v;
    }

    // ---- epilogue: normalize, +conv bias, LePE 3x3 from Vt, store bf16 X ----
    #pragma unroll
    for (int qq = 0; qq < 4; ++qq) {
        const int t = qbase + qq * 16 + nn;
        const int h = t >> 3, wi = t & 7;
        #pragma unroll
        for (int nt = 0; nt < 2; ++nt) {
            const int chb = nt * 16 + q4 * 4;
            float o[4];
            #pragma unroll
            for (int r = 0; r < 4; ++r)
                o[r] = acc[qq][nt][r] * inv[qq] + cb[chb + r];
            #pragma unroll
            for (int dh = -1; dh <= 1; ++dh) {
                const int hh = h + dh;
                if (hh < 0 || hh >= RESO) continue;
                #pragma unroll
                for (int dw = -1; dw <= 1; ++dw) {
                    const int ww = wi + dw;
                    if (ww < 0 || ww >= 8) continue;
                    const int tj  = hh * 8 + ww;
                    const int wof = (dh + 1) * 3 + (dw + 1);
                    #pragma unroll
                    for (int r = 0; r < 4; ++r)
                        o[r] += cw[(chb + r) * 9 + wof] * bf2f(Vt[(chb + r) * VSTRIDE + tj]);
                }
            }
            ushort4 st;
            st.x = f2bf(o[0]); st.y = f2bf(o[1]); st.z = f2bf(o[2]); st.w = f2bf(o[3]);
            *(ushort4*)&X[((size_t)bw * WIN + t) * DIM + head * HD + chb] = st;
        }
    }
}

// ---------------------------------------------------------------------------
// Kernel 2: MFMA projection GEMM  out = X @ W^T + b, CSwin2img permuted rows.
// Grid: 512 blocks (128 m-blocks x 4 n-blocks) x 256 thr (4 waves).
// ---------------------------------------------------------------------------
__global__ __launch_bounds__(256, 4)
void proj_mfma_kernel(const unsigned short* __restrict__ X,
                      const float* __restrict__ pw,
                      const float* __restrict__ pb,
                      float* __restrict__ out)
{
    __shared__ alignas(16) unsigned short Wl[64 * WPAD];   // 33.8 KB

    const int bx   = blockIdx.x;
    const int mblk = bx >> 2;            // 0..127 -> 256 tokens each
    const int nblk = bx & 3;             // 0..3   -> 64 channels each
    const int tid  = threadIdx.x;
    const int n0   = nblk * 64;

    // ---- stage W[n0..n0+63][0..255] -> bf16 LDS (4 threads per row) ----
    {
        const int row = tid >> 2;
        const int cb0 = (tid & 3) * 64;
        #pragma unroll
        for (int c = 0; c < 64; c += 8) {
            const float4 w0 = *(const float4*)&pw[(size_t)(n0 + row) * DIM + cb0 + c];
            const float4 w1 = *(const float4*)&pw[(size_t)(n0 + row) * DIM + cb0 + c + 4];
            uint4 pk;
            pk.x = pk2(w0.x, w0.y); pk.y = pk2(w0.z, w0.w);
            pk.z = pk2(w1.x, w1.y); pk.w = pk2(w1.z, w1.w);
            *(uint4*)&Wl[row * WPAD + cb0 + c] = pk;
        }
    }
    __syncthreads();

    const int lane = tid & 63, wid = tid >> 6;
    const int q4 = lane >> 4, nn = lane & 15;
    const int mwave = mblk * 256 + wid * 64;     // 64 tokens per wave

    floatx4 acc[4][4];                            // [nt][mt]
    #pragma unroll
    for (int i = 0; i < 4; ++i)
        #pragma unroll
        for (int j = 0; j < 4; ++j)
            acc[i][j] = (floatx4){0.f, 0.f, 0.f, 0.f};

    for (int kk = 0; kk < 8; ++kk) {
        short8 af[4], bf[4];
        #pragma unroll
        for (int nt = 0; nt < 4; ++nt)
            af[nt] = *(const short8*)&Wl[(nt * 16 + nn) * WPAD + kk * 32 + q4 * 8];
        #pragma unroll
        for (int mt = 0; mt < 4; ++mt) {
            const int m = mwave + mt * 16 + nn;
            bf[mt] = *(const short8*)&X[(size_t)m * DIM + kk * 32 + q4 * 8];
        }
        #pragma unroll
        for (int nt = 0; nt < 4; ++nt)
            #pragma unroll
            for (int mt = 0; mt < 4; ++mt)
                acc[nt][mt] = __builtin_amdgcn_mfma_f32_16x16x32_bf16(af[nt], bf[mt], acc[nt][mt], 0, 0, 0);
    }

    // ---- bias + permuted store (float4 per lane per tile) ----
    float4 bias[4];
    #pragma unroll
    for (int nt = 0; nt < 4; ++nt)
        bias[nt] = *(const float4*)&pb[n0 + nt * 16 + q4 * 4];

    size_t rowoff[4];
    #pragma unroll
    for (int mt = 0; mt < 4; ++mt) {
        const int m  = mwave + mt * 16 + nn;
        const int bw = m >> 9, t = m & 511;
        const int bb = bw >> 3, wx = bw & 7, hh = t >> 3, wi = t & 7;
        rowoff[mt] = ((size_t)bb * SEQL + (size_t)hh * RESO + wx * 8 + wi) * DIM;
    }

    #pragma unroll
    for (int nt = 0; nt < 4; ++nt)
        #pragma unroll
        for (int mt = 0; mt < 4; ++mt) {
            float4 v;
            v.x = acc[nt][mt][0] + bias[nt].x;
            v.y = acc[nt][mt][1] + bias[nt].y;
            v.z = acc[nt][mt][2] + bias[nt].z;
            v.w = acc[nt][mt][3] + bias[nt].w;
            *(float4*)&out[rowoff[mt] + n0 + nt * 16 + q4 * 4] = v;
        }
}

extern "C" void kernel_launch(void* const* d_in, const int* in_sizes, int n_in,
                              void* d_out, int out_size, void* d_ws, size_t ws_size,
                              hipStream_t stream)
{
    const float* qkv    = (const float*)d_in[0];
    const float* scale  = (const float*)d_in[1];
    const float* proj_w = (const float*)d_in[2];
    const float* proj_b = (const float*)d_in[3];
    const float* conv_w = (const float*)d_in[4];
    const float* conv_b = (const float*)d_in[5];

    unsigned short* X = (unsigned short*)d_ws;   // 64*512*256 bf16 = 16 MiB

    attn_mfma_kernel<<<dim3(BATCH * NH * 8), dim3(512), 0, stream>>>(
        qkv, scale, conv_w, conv_b, X);

    proj_mfma_kernel<<<dim3(512), dim3(256), 0, stream>>>(
        X, proj_w, proj_b, (float*)d_out);
}